// Round 2
// baseline (2691.330 us; speedup 1.0000x reference)
//
#include <hip/hip_runtime.h>
#include <math.h>

#define NPARTS 20
#define BATCH  2048
#define TOTALV 991
#define MAXN   92
#define NEPS   9

__constant__ int   c_start[NPARTS] = {0,45,106,149,194,286,320,361,423,467,511,569,611,651,711,752,787,851,879,929};
__constant__ int   c_n[NPARTS]     = {45,61,43,45,92,34,41,62,44,44,58,42,40,60,41,35,64,28,50,62};
__constant__ float c_eps[NEPS]     = {64.0f,16.0f,4.0f,1.0f,0.25f,0.0625f,0.015625f,0.00390625f,0.0025f};

#define LOG2E 1.4426950408889634f
#define LN2   0.6931471805599453f

// One block per (batch, part). Thread t owns row/col t (t < n). All four
// logsumexp reductions per eps share one merged k-loop over LDS float4 tables:
//   w_ft  = xs·Y.xyz + ax + Y.w        (Y.w = g[k]*sc + ay_k + lA)
//   w_gt  = ys·X.xyz + ay + X.w        (X.w = f[k]*sc + ax_k + lA)
//   w_px  = xs·X.xyz + ax + TX[k]      (TX  = px[k]*sc + ax_k + lA)
//   w_py  = ys·Y.xyz + ay + TPY[k]     (TPY = py[k]*sc + ay_k + lA)
// Everything in log2-space (exp2/log2 are the native v_exp/v_log ops).
__global__ __launch_bounds__(128) void sinkhorn_kernel(
    const float* __restrict__ pred, const float* __restrict__ pc,
    float* __restrict__ partial)
{
    const int bid  = blockIdx.x;
    const int part = bid % NPARTS;
    const int b    = bid / NPARTS;
    const int st   = c_start[part];
    const int n    = c_n[part];
    const int t    = threadIdx.x;

    __shared__ float4 X4[MAXN];
    __shared__ float4 Y4[MAXN];
    __shared__ float  TX[MAXN];
    __shared__ float  TPY[MAXN];
    __shared__ float  wsum[2];

    float x0=0.f,x1=0.f,x2=0.f,y0=0.f,y1=0.f,y2=0.f,xn2=0.f,yn2=0.f;
    const bool act = (t < n);
    if (act) {
        const float* xp = pred + ((size_t)b*TOTALV + st + t)*3;
        const float* yp = pc   + ((size_t)b*TOTALV + st + t)*3;
        x0=xp[0]; x1=xp[1]; x2=xp[2];
        y0=yp[0]; y1=yp[1]; y2=yp[2];
        xn2 = x0*x0 + x1*x1 + x2*x2;
        yn2 = y0*y0 + y1*y1 + y2*y2;
    }
    const float lA = -log2f((float)n);   // loga*log2e  (== logb*log2e, n==m)
    float f=0.f, g=0.f, px=0.f, py=0.f;

    for (int it=0; it<NEPS; ++it) {
        const float eps = c_eps[it];
        const float sc  = LOG2E / eps;   // fold log2e into 1/eps
        const float ce  = -eps * LN2;    // -eps * ln2 (back-conversion)

        const float xs0=x0*sc, xs1=x1*sc, xs2=x2*sc;
        const float ys0=y0*sc, ys1=y1*sc, ys2=y2*sc;
        const float ax = -0.5f*xn2*sc;
        const float ay = -0.5f*yn2*sc;

        if (act) {
            X4[t]  = make_float4(x0, x1, x2, fmaf(f, sc, ax + lA));
            Y4[t]  = make_float4(y0, y1, y2, fmaf(g, sc, ay + lA));
            TX[t]  = fmaf(px, sc, ax + lA);
            TPY[t] = fmaf(py, sc, ay + lA);
        }
        __syncthreads();

        float mft=-INFINITY, mgt=-INFINITY, mpx=-INFINITY, mpy=-INFINITY;
        if (act) {
            #pragma unroll 4
            for (int k=0; k<n; ++k) {
                const float4 X = X4[k]; const float4 Y = Y4[k];
                const float tx = TX[k]; const float tpy = TPY[k];
                const float wft = fmaf(xs0,Y.x, fmaf(xs1,Y.y, fmaf(xs2,Y.z, ax+Y.w)));
                const float wpx = fmaf(xs0,X.x, fmaf(xs1,X.y, fmaf(xs2,X.z, ax+tx)));
                const float wgt = fmaf(ys0,X.x, fmaf(ys1,X.y, fmaf(ys2,X.z, ay+X.w)));
                const float wpy = fmaf(ys0,Y.x, fmaf(ys1,Y.y, fmaf(ys2,Y.z, ay+tpy)));
                mft = fmaxf(mft, wft);
                mpx = fmaxf(mpx, wpx);
                mgt = fmaxf(mgt, wgt);
                mpy = fmaxf(mpy, wpy);
            }
        }
        float sft=0.f, sgt=0.f, spx=0.f, spy=0.f;
        if (act) {
            #pragma unroll 4
            for (int k=0; k<n; ++k) {
                const float4 X = X4[k]; const float4 Y = Y4[k];
                const float tx = TX[k]; const float tpy = TPY[k];
                const float wft = fmaf(xs0,Y.x, fmaf(xs1,Y.y, fmaf(xs2,Y.z, ax+Y.w)));
                const float wpx = fmaf(xs0,X.x, fmaf(xs1,X.y, fmaf(xs2,X.z, ax+tx)));
                const float wgt = fmaf(ys0,X.x, fmaf(ys1,X.y, fmaf(ys2,X.z, ay+X.w)));
                const float wpy = fmaf(ys0,Y.x, fmaf(ys1,Y.y, fmaf(ys2,Y.z, ay+tpy)));
                sft += exp2f(wft - mft);
                spx += exp2f(wpx - mpx);
                sgt += exp2f(wgt - mgt);
                spy += exp2f(wpy - mpy);
            }
            // f_new = 0.5*(f + ft), ft = -eps*lse = ce*(m + log2(s)); same form for all four
            f  = 0.5f*(f  + ce*(mft + log2f(sft)));
            g  = 0.5f*(g  + ce*(mgt + log2f(sgt)));
            px = 0.5f*(px + ce*(mpx + log2f(spx)));
            py = 0.5f*(py + ce*(mpy + log2f(spy)));
        }
        __syncthreads();   // tables consumed; safe to rebuild next iter
    }

    // block partial: [sum(f-px) + sum(g-py)] / n / BATCH
    float d = act ? (f - px + g - py) : 0.f;
    #pragma unroll
    for (int o=32; o>0; o>>=1) d += __shfl_down(d, o, 64);
    if ((t & 63) == 0) wsum[t >> 6] = d;
    __syncthreads();
    if (t == 0) partial[bid] = (wsum[0] + wsum[1]) * (1.0f / ((float)n * (float)BATCH));
}

__global__ __launch_bounds__(1024) void reduce_kernel(
    const float* __restrict__ partial, float* __restrict__ out, int nb)
{
    const int t = threadIdx.x;
    double acc = 0.0;
    for (int i=t; i<nb; i+=blockDim.x) acc += (double)partial[i];
    #pragma unroll
    for (int o=32; o>0; o>>=1) acc += __shfl_down(acc, o, 64);
    __shared__ double ws[16];
    if ((t & 63) == 0) ws[t >> 6] = acc;
    __syncthreads();
    if (t == 0) {
        double tot = 0.0;
        const int nw = 1024/64;
        for (int w=0; w<nw; ++w) tot += ws[w];
        out[0] = (float)tot;
    }
}

extern "C" void kernel_launch(void* const* d_in, const int* in_sizes, int n_in,
                              void* d_out, int out_size, void* d_ws, size_t ws_size,
                              hipStream_t stream) {
    const float* pred = (const float*)d_in[0];
    const float* pc   = (const float*)d_in[1];
    float* partial = (float*)d_ws;                 // BATCH*NPARTS floats = 160 KB
    float* out     = (float*)d_out;
    const int nb = BATCH * NPARTS;
    sinkhorn_kernel<<<nb, 128, 0, stream>>>(pred, pc, partial);
    reduce_kernel<<<1, 1024, 0, stream>>>(partial, out, nb);
}

// Round 3
// 2023.366 us; speedup vs baseline: 1.3301x; 1.3301x over previous
//
#include <hip/hip_runtime.h>
#include <math.h>

#define NPARTS 20
#define BATCH  2048
#define TOTALV 991
#define NEPS   9

#define LOG2E 1.4426950408889634f
#define LN2   0.6931471805599453f

__constant__ int   c_start[NPARTS] = {0,45,106,149,194,286,320,361,423,467,511,569,611,651,711,752,787,851,879,929};
__constant__ int   c_n[NPARTS]     = {45,61,43,45,92,34,41,62,44,44,58,42,40,60,41,35,64,28,50,62};
__constant__ float c_eps[NEPS]     = {64.0f,16.0f,4.0f,1.0f,0.25f,0.0625f,0.015625f,0.00390625f,0.0025f};

// Wave-local problem packing: one 256-thread block per batch item, 4 waves.
// Each lane owns R=4 rows (r0, r0+h, r0+2h, r0+3h; h=ceil(n/4)) of ONE part.
// Parts are bin-packed into waves (sum of h's <= 64, similar n together):
//  w0: p4(92,h23) p7(62,16) p19(62,16) p15(35,9)          -> 64 lanes, maxn 92
//  w1: p16(64,16) p1(61,16) p13(60,15) p12(40,10) p17(28,7)-> 64 lanes, maxn 64
//  w2: p10(58,15) p18(50,13) p0(45,12) p3(45,12) p8(44,11) -> 63 lanes, maxn 58
//  w3: p9(44,11) p2(43,11) p11(42,11) p6(41,11) p14(41,11) p5(34,9) -> 64, maxn 44
__constant__ int c_w_np[4]       = {4,5,5,6};
__constant__ int c_w_part[4][6]  = {{4,7,19,15,0,0},{16,1,13,12,17,0},{10,18,0,3,8,0},{9,2,11,6,14,5}};
__constant__ int c_w_lane0[4][7] = {{0,23,39,55,64,64,64},{0,16,32,47,57,64,64},{0,15,28,40,52,63,64},{0,11,22,33,44,55,64}};
__constant__ int c_w_tb[4][6]    = {{0,92,154,216,0,0},{0,64,125,185,225,0},{0,58,108,153,198,0},{0,44,87,129,170,211}};

// Tables (per wave region of 256 rows): sX[k]=(sc*x_k, fterm_k), sY[k]=(sc*y_k, gterm_k),
// sT[k]=(pxterm_k, pyterm_k), where *term_k = v_k*sc + a_k + lA and a_k = -0.5*|.|^2*sc.
// w'_ft = x_i . (sc*y_k) + gterm_k   (row-side ax_i cancels in exp2, added to max at end)
__global__ __launch_bounds__(256) void sinkhorn_kernel(
    const float* __restrict__ pred, const float* __restrict__ pc,
    float* __restrict__ partial)
{
    __shared__ float4 sX[1024];
    __shared__ float4 sY[1024];
    __shared__ float2 sT[1024];

    const int b    = blockIdx.x;
    const int w    = threadIdx.x >> 6;
    const int lane = threadIdx.x & 63;

    int pj = -1;
    const int np = c_w_np[w];
    #pragma unroll
    for (int j = 0; j < 6; ++j)
        if (j < np && lane >= c_w_lane0[w][j] && lane < c_w_lane0[w][j+1]) pj = j;
    const bool lact = (pj >= 0);
    const int jj   = lact ? pj : 0;
    const int part = c_w_part[w][jj];
    const int st   = c_start[part];
    const int n    = lact ? c_n[part] : 0;
    const int h    = (n + 3) >> 2;
    const int r0   = lact ? (lane - c_w_lane0[w][jj]) : 0;
    const int tb   = (w << 8) + c_w_tb[w][jj];

    float x0[4],x1[4],x2[4],y0[4],y1[4],y2[4],xh[4],yh[4];
    bool ra[4];
    #pragma unroll
    for (int j=0;j<4;++j) {
        const int r = r0 + j*h;
        ra[j] = lact && (r < n);
        if (ra[j]) {
            const float* xp = pred + ((size_t)b*TOTALV + st + r)*3;
            const float* yp = pc   + ((size_t)b*TOTALV + st + r)*3;
            x0[j]=xp[0]; x1[j]=xp[1]; x2[j]=xp[2];
            y0[j]=yp[0]; y1[j]=yp[1]; y2[j]=yp[2];
        } else { x0[j]=0.f;x1[j]=0.f;x2[j]=0.f;y0[j]=0.f;y1[j]=0.f;y2[j]=0.f; }
        xh[j] = -0.5f*(x0[j]*x0[j]+x1[j]*x1[j]+x2[j]*x2[j]);
        yh[j] = -0.5f*(y0[j]*y0[j]+y1[j]*y1[j]+y2[j]*y2[j]);
    }
    const float lA = lact ? -log2f((float)n) : 0.f;
    float f[4]={0,0,0,0}, g[4]={0,0,0,0}, px[4]={0,0,0,0}, py[4]={0,0,0,0};

    for (int it=0; it<NEPS; ++it) {
        const float eps = c_eps[it];
        const float sc  = LOG2E/eps;
        const float ce  = -eps*LN2;
        float ax[4], ay[4];
        #pragma unroll
        for (int j=0;j<4;++j) { ax[j]=xh[j]*sc; ay[j]=yh[j]*sc; }

        // build wave-local tables (f,g,px,py all pre-update: matches reference order)
        #pragma unroll
        for (int j=0;j<4;++j) if (ra[j]) {
            const int tr = tb + r0 + j*h;
            sX[tr] = make_float4(x0[j]*sc, x1[j]*sc, x2[j]*sc, fmaf(f[j],  sc, ax[j]+lA));
            sY[tr] = make_float4(y0[j]*sc, y1[j]*sc, y2[j]*sc, fmaf(g[j],  sc, ay[j]+lA));
            sT[tr] = make_float2(fmaf(px[j], sc, ax[j]+lA), fmaf(py[j], sc, ay[j]+lA));
        }
        // same-wave DS ops are in-order; reads below see the writes above.

        float mf[4],mg[4],mp[4],mq[4];
        #pragma unroll
        for (int j=0;j<4;++j){ mf[j]=-INFINITY; mg[j]=-INFINITY; mp[j]=-INFINITY; mq[j]=-INFINITY; }
        #pragma unroll 2
        for (int k=0;k<n;++k) {
            const float4 XA = sX[tb+k];
            const float4 YA = sY[tb+k];
            const float2 TT = sT[tb+k];
            #pragma unroll
            for (int j=0;j<4;++j) {
                const float wf = fmaf(x0[j],YA.x, fmaf(x1[j],YA.y, fmaf(x2[j],YA.z, YA.w)));
                const float wq = fmaf(y0[j],YA.x, fmaf(y1[j],YA.y, fmaf(y2[j],YA.z, TT.y)));
                const float wg = fmaf(y0[j],XA.x, fmaf(y1[j],XA.y, fmaf(y2[j],XA.z, XA.w)));
                const float wp = fmaf(x0[j],XA.x, fmaf(x1[j],XA.y, fmaf(x2[j],XA.z, TT.x)));
                mf[j]=fmaxf(mf[j],wf); mq[j]=fmaxf(mq[j],wq);
                mg[j]=fmaxf(mg[j],wg); mp[j]=fmaxf(mp[j],wp);
            }
        }
        float sf[4]={0,0,0,0}, sg[4]={0,0,0,0}, sp[4]={0,0,0,0}, sq[4]={0,0,0,0};
        #pragma unroll 2
        for (int k=0;k<n;++k) {
            const float4 XA = sX[tb+k];
            const float4 YA = sY[tb+k];
            const float2 TT = sT[tb+k];
            #pragma unroll
            for (int j=0;j<4;++j) {
                const float wf = fmaf(x0[j],YA.x, fmaf(x1[j],YA.y, fmaf(x2[j],YA.z, YA.w)));
                const float wq = fmaf(y0[j],YA.x, fmaf(y1[j],YA.y, fmaf(y2[j],YA.z, TT.y)));
                const float wg = fmaf(y0[j],XA.x, fmaf(y1[j],XA.y, fmaf(y2[j],XA.z, XA.w)));
                const float wp = fmaf(x0[j],XA.x, fmaf(x1[j],XA.y, fmaf(x2[j],XA.z, TT.x)));
                sf[j] += exp2f(wf - mf[j]); sq[j] += exp2f(wq - mq[j]);
                sg[j] += exp2f(wg - mg[j]); sp[j] += exp2f(wp - mp[j]);
            }
        }
        #pragma unroll
        for (int j=0;j<4;++j) {
            f[j]  = 0.5f*(f[j]  + ce*(ax[j] + mf[j] + log2f(sf[j])));
            g[j]  = 0.5f*(g[j]  + ce*(ay[j] + mg[j] + log2f(sg[j])));
            px[j] = 0.5f*(px[j] + ce*(ax[j] + mp[j] + log2f(sp[j])));
            py[j] = 0.5f*(py[j] + ce*(ay[j] + mq[j] + log2f(sq[j])));
        }
        // next-iter table writes are program-ordered after all reads (same wave): safe.
    }

    float d = 0.f;
    #pragma unroll
    for (int j=0;j<4;++j) if (ra[j]) d += (f[j]-px[j]) + (g[j]-py[j]);
    if (lact) d *= 1.0f/(float)n;
    #pragma unroll
    for (int o=32;o>0;o>>=1) d += __shfl_down(d, o, 64);
    if (lane==0) partial[(b<<2)+w] = d * (1.0f/(float)BATCH);
    // no __syncthreads anywhere: waves are fully independent
}

__global__ __launch_bounds__(1024) void reduce_kernel(
    const float* __restrict__ partial, float* __restrict__ out, int nb)
{
    const int t = threadIdx.x;
    double acc = 0.0;
    for (int i=t; i<nb; i+=blockDim.x) acc += (double)partial[i];
    #pragma unroll
    for (int o=32; o>0; o>>=1) acc += __shfl_down(acc, o, 64);
    __shared__ double ws[16];
    if ((t & 63) == 0) ws[t >> 6] = acc;
    __syncthreads();
    if (t == 0) {
        double tot = 0.0;
        for (int v=0; v<1024/64; ++v) tot += ws[v];
        out[0] = (float)tot;
    }
}

extern "C" void kernel_launch(void* const* d_in, const int* in_sizes, int n_in,
                              void* d_out, int out_size, void* d_ws, size_t ws_size,
                              hipStream_t stream) {
    const float* pred = (const float*)d_in[0];
    const float* pc   = (const float*)d_in[1];
    float* partial = (float*)d_ws;                  // BATCH*4 floats = 32 KB
    float* out     = (float*)d_out;
    sinkhorn_kernel<<<BATCH, 256, 0, stream>>>(pred, pc, partial);
    reduce_kernel<<<1, 1024, 0, stream>>>(partial, out, BATCH*4);
}

// Round 4
// 1467.288 us; speedup vs baseline: 1.8342x; 1.3790x over previous
//
#include <hip/hip_runtime.h>
#include <math.h>

typedef float f32x2 __attribute__((ext_vector_type(2)));

#define NPARTS 20
#define BATCH  2048
#define TOTALV 991
#define NEPS   9

#define LOG2E 1.4426950408889634f
#define LN2   0.6931471805599453f

__constant__ int   c_start[NPARTS] = {0,45,106,149,194,286,320,361,423,467,511,569,611,651,711,752,787,851,879,929};
__constant__ int   c_n[NPARTS]     = {45,61,43,45,92,34,41,62,44,44,58,42,40,60,41,35,64,28,50,62};
__constant__ float c_eps[NEPS]     = {64.0f,16.0f,4.0f,1.0f,0.25f,0.0625f,0.015625f,0.00390625f,0.0025f};

// One 64-thread block = one wave = one (batch item, wave-slot). Parts bin-packed
// into 4 wave-slots (R=4 rows/lane, h=ceil(n/4) lanes/part):
//  w0: p4(92) p7(62) p19(62) p15(35) ; w1: p16(64) p1(61) p13(60) p12(40) p17(28)
//  w2: p10(58) p18(50) p0(45) p3(45) p8(44) ; w3: p9(44) p2(43) p11(42) p6(41) p14(41) p5(34)
__constant__ int c_w_np[4]       = {4,5,5,6};
__constant__ int c_w_part[4][6]  = {{4,7,19,15,0,0},{16,1,13,12,17,0},{10,18,0,3,8,0},{9,2,11,6,14,5}};
__constant__ int c_w_lane0[4][7] = {{0,23,39,55,64,64,64},{0,16,32,47,57,64,64},{0,15,28,40,52,63,64},{0,11,22,33,44,55,64}};
__constant__ int c_w_tb[4][6]    = {{0,92,154,216,0,0},{0,64,125,185,225,0},{0,58,108,153,198,0},{0,44,87,129,170,211}};

static __device__ __forceinline__ f32x2 sp(float v){ f32x2 r; r.x=v; r.y=v; return r; }
static __device__ __forceinline__ float gc(f32x2 v, int c){ return c ? v.y : v.x; }
static __device__ __forceinline__ f32x2 pexp2(f32x2 v){
    f32x2 r; r.x=__builtin_amdgcn_exp2f(v.x); r.y=__builtin_amdgcn_exp2f(v.y); return r;
}
#define PFMA(a,b,c) __builtin_elementwise_fma(a,b,c)
#define PMAX(a,b)   __builtin_elementwise_max(a,b)

// Tables: sX[k]=(sc*x_k, f_k*sc+ax_k+lA), sY[k]=(sc*y_k, g_k*sc+ay_k+lA),
// sT[k]=(px_k*sc+ax_k+lA, py_k*sc+ay_k+lA). Row-side ax_i cancels in exp2,
// re-added at finalize. Rows stay RAW in registers (packed f32x2 pairs).
__global__ __launch_bounds__(64) void sinkhorn_kernel(
    const float* __restrict__ pred, const float* __restrict__ pc,
    float* __restrict__ partial)
{
    __shared__ float4 sX[256];
    __shared__ float4 sY[256];
    __shared__ float2 sT[256];

    const int bid  = blockIdx.x;
    const int b    = bid >> 2;
    const int w    = bid & 3;
    const int lane = threadIdx.x;

    int pj = -1;
    const int np = c_w_np[w];
    #pragma unroll
    for (int j = 0; j < 6; ++j)
        if (j < np && lane >= c_w_lane0[w][j] && lane < c_w_lane0[w][j+1]) pj = j;
    const bool lact = (pj >= 0);
    const int jj   = lact ? pj : 0;
    const int part = c_w_part[w][jj];
    const int st   = c_start[part];
    const int n    = lact ? c_n[part] : 0;
    const int h    = (n + 3) >> 2;
    const int r0   = lact ? (lane - c_w_lane0[w][jj]) : 0;
    const int tb   = c_w_tb[w][jj];

    f32x2 X0[2],X1[2],X2[2],Y0[2],Y1[2],Y2[2];
    float xh[4], yh[4];
    bool ra[4];
    #pragma unroll
    for (int j=0;j<4;++j) {
        const int r = r0 + j*h;
        ra[j] = lact && (r < n);
        float a0=0.f,a1=0.f,a2=0.f,b0=0.f,b1=0.f,b2=0.f;
        if (ra[j]) {
            const float* xp = pred + ((size_t)b*TOTALV + st + r)*3;
            const float* yp = pc   + ((size_t)b*TOTALV + st + r)*3;
            a0=xp[0]; a1=xp[1]; a2=xp[2];
            b0=yp[0]; b1=yp[1]; b2=yp[2];
        }
        const int p=j>>1;
        if ((j&1)==0) { X0[p].x=a0; X1[p].x=a1; X2[p].x=a2; Y0[p].x=b0; Y1[p].x=b1; Y2[p].x=b2; }
        else          { X0[p].y=a0; X1[p].y=a1; X2[p].y=a2; Y0[p].y=b0; Y1[p].y=b1; Y2[p].y=b2; }
        xh[j] = -0.5f*(a0*a0+a1*a1+a2*a2);
        yh[j] = -0.5f*(b0*b0+b1*b1+b2*b2);
    }
    const float lA = lact ? -log2f((float)n) : 0.f;
    float f[4]={0,0,0,0}, g[4]={0,0,0,0}, px[4]={0,0,0,0}, py[4]={0,0,0,0};
    float ax[4], ay[4];

    for (int it=0; it<NEPS; ++it) {
        const float eps = c_eps[it];
        const float sc  = LOG2E/eps;
        const float ce  = -eps*LN2;
        #pragma unroll
        for (int j=0;j<4;++j) { ax[j]=xh[j]*sc; ay[j]=yh[j]*sc; }

        // build tables (pre-update f,g,px,py: matches reference order).
        // Same-wave DS ops are program-ordered; no barrier needed.
        #pragma unroll
        for (int j=0;j<4;++j) if (ra[j]) {
            const int p=j>>1, c=j&1;
            const int tr = tb + r0 + j*h;
            sX[tr] = make_float4(gc(X0[p],c)*sc, gc(X1[p],c)*sc, gc(X2[p],c)*sc, fmaf(f[j],  sc, ax[j]+lA));
            sY[tr] = make_float4(gc(Y0[p],c)*sc, gc(Y1[p],c)*sc, gc(Y2[p],c)*sc, fmaf(g[j],  sc, ay[j]+lA));
            sT[tr] = make_float2(fmaf(px[j], sc, ax[j]+lA), fmaf(py[j], sc, ay[j]+lA));
        }

        f32x2 MF[2],MG[2],MP[2],MQ[2];
        #pragma unroll
        for (int p=0;p<2;++p){ MF[p]=sp(-INFINITY); MG[p]=sp(-INFINITY); MP[p]=sp(-INFINITY); MQ[p]=sp(-INFINITY); }

        // pass 1: max (prefetch k+1; tb+n <= 253 so tb+k+1 stays in bounds)
        float4 XA = sX[tb], YA = sY[tb]; float2 TT = sT[tb];
        for (int k=0; k<n; ++k) {
            const float4 XN = sX[tb+k+1];
            const float4 YN = sY[tb+k+1];
            const float2 TN = sT[tb+k+1];
            #pragma unroll
            for (int p=0;p<2;++p) {
                const f32x2 wf = PFMA(X0[p],sp(YA.x), PFMA(X1[p],sp(YA.y), PFMA(X2[p],sp(YA.z), sp(YA.w))));
                const f32x2 wq = PFMA(Y0[p],sp(YA.x), PFMA(Y1[p],sp(YA.y), PFMA(Y2[p],sp(YA.z), sp(TT.y))));
                const f32x2 wg = PFMA(Y0[p],sp(XA.x), PFMA(Y1[p],sp(XA.y), PFMA(Y2[p],sp(XA.z), sp(XA.w))));
                const f32x2 wp = PFMA(X0[p],sp(XA.x), PFMA(X1[p],sp(XA.y), PFMA(X2[p],sp(XA.z), sp(TT.x))));
                MF[p]=PMAX(MF[p],wf); MQ[p]=PMAX(MQ[p],wq);
                MG[p]=PMAX(MG[p],wg); MP[p]=PMAX(MP[p],wp);
            }
            XA=XN; YA=YN; TT=TN;
        }

        // pass 2: exp2-sum
        f32x2 SF[2],SG[2],SP[2],SQ[2];
        #pragma unroll
        for (int p=0;p<2;++p){ SF[p]=sp(0.f); SG[p]=sp(0.f); SP[p]=sp(0.f); SQ[p]=sp(0.f); }
        XA = sX[tb]; YA = sY[tb]; TT = sT[tb];
        for (int k=0; k<n; ++k) {
            const float4 XN = sX[tb+k+1];
            const float4 YN = sY[tb+k+1];
            const float2 TN = sT[tb+k+1];
            #pragma unroll
            for (int p=0;p<2;++p) {
                const f32x2 wf = PFMA(X0[p],sp(YA.x), PFMA(X1[p],sp(YA.y), PFMA(X2[p],sp(YA.z), sp(YA.w))));
                const f32x2 wq = PFMA(Y0[p],sp(YA.x), PFMA(Y1[p],sp(YA.y), PFMA(Y2[p],sp(YA.z), sp(TT.y))));
                const f32x2 wg = PFMA(Y0[p],sp(XA.x), PFMA(Y1[p],sp(XA.y), PFMA(Y2[p],sp(XA.z), sp(XA.w))));
                const f32x2 wp = PFMA(X0[p],sp(XA.x), PFMA(X1[p],sp(XA.y), PFMA(X2[p],sp(XA.z), sp(TT.x))));
                SF[p] += pexp2(wf - MF[p]);
                SQ[p] += pexp2(wq - MQ[p]);
                SG[p] += pexp2(wg - MG[p]);
                SP[p] += pexp2(wp - MP[p]);
            }
            XA=XN; YA=YN; TT=TN;
        }

        #pragma unroll
        for (int j=0;j<4;++j) {
            const int p=j>>1, c=j&1;
            f[j]  = 0.5f*(f[j]  + ce*(ax[j] + gc(MF[p],c) + __builtin_amdgcn_logf(gc(SF[p],c))));
            g[j]  = 0.5f*(g[j]  + ce*(ay[j] + gc(MG[p],c) + __builtin_amdgcn_logf(gc(SG[p],c))));
            px[j] = 0.5f*(px[j] + ce*(ax[j] + gc(MP[p],c) + __builtin_amdgcn_logf(gc(SP[p],c))));
            py[j] = 0.5f*(py[j] + ce*(ay[j] + gc(MQ[p],c) + __builtin_amdgcn_logf(gc(SQ[p],c))));
        }
        // next-iter table writes are program-ordered after all reads (same wave): safe.
    }

    float d = 0.f;
    #pragma unroll
    for (int j=0;j<4;++j) if (ra[j]) d += (f[j]-px[j]) + (g[j]-py[j]);
    if (lact) d *= 1.0f/(float)n;
    #pragma unroll
    for (int o=32;o>0;o>>=1) d += __shfl_down(d, o, 64);
    if (lane==0) partial[bid] = d * (1.0f/(float)BATCH);
}

__global__ __launch_bounds__(1024) void reduce_kernel(
    const float* __restrict__ partial, float* __restrict__ out, int nb)
{
    const int t = threadIdx.x;
    double acc = 0.0;
    for (int i=t; i<nb; i+=blockDim.x) acc += (double)partial[i];
    #pragma unroll
    for (int o=32; o>0; o>>=1) acc += __shfl_down(acc, o, 64);
    __shared__ double ws[16];
    if ((t & 63) == 0) ws[t >> 6] = acc;
    __syncthreads();
    if (t == 0) {
        double tot = 0.0;
        for (int v=0; v<1024/64; ++v) tot += ws[v];
        out[0] = (float)tot;
    }
}

extern "C" void kernel_launch(void* const* d_in, const int* in_sizes, int n_in,
                              void* d_out, int out_size, void* d_ws, size_t ws_size,
                              hipStream_t stream) {
    const float* pred = (const float*)d_in[0];
    const float* pc   = (const float*)d_in[1];
    float* partial = (float*)d_ws;                  // BATCH*4 floats = 32 KB
    float* out     = (float*)d_out;
    sinkhorn_kernel<<<BATCH*4, 64, 0, stream>>>(pred, pc, partial);
    reduce_kernel<<<1, 1024, 0, stream>>>(partial, out, BATCH*4);
}